// Round 14
// baseline (515.185 us; speedup 1.0000x reference)
//
#include <hip/hip_runtime.h>
#include <hip/hip_bf16.h>

#define U_CNT 339
#define S_CNT 5825
#define N_CNT 6164          // U + S
#define D_DIM 128
#define R_DIM 32
#define B_CNT 500000
#define M_EDGE 400000       // 2*NNZ (symmetrized)
#define H_DIM 64
#define LN_EPS 1e-5f

// ---- transposed E layout: Et[d][col], col(u)=u (0..351 pad), col(s)=352+s ----
#define NPAD 6208           // 352 (u pad) + 5856 (s pad)
#define COL_S0 352
#define ET_U16 (128 * NPAD) // ushorts per plane

// ---- adjacency packed as MFMA B-fragments (bf16) ----
#define KT_U 11             // u as K: 352/32
#define KT_S 183            // s as K: 5856/32
#define NT_S 365            // s as N: 5840/16
#define NT_U 22             // u as N: 352/16
#define PKS_U16 (KT_U * NT_S * 512)   // B[k=u][n=s]
#define PKU_U16 (KT_S * NT_U * 512)   // B[k=s][n=u]

// hop grid: s-side 4 nt/block (all 8 m-tiles per wave, B reused in regs);
// u-side 1 nt/block, 4-way split-K + LDS reduce
#define S_HOP_BLOCKS 92     // ceil(NT_S/4)
#define U_HOP_BLOCKS NT_U   // 22
#define HOP_BLOCKS (S_HOP_BLOCKS + U_HOP_BLOCKS)   // 114
#define U_KCHUNK 46         // ceil(KT_S/4)

// fp32 weight-block offsets (elements)
#define WF_B1   4096
#define WF_G1   4160
#define WF_BE1  4224
#define WF_B2   4288
#define WF_G2   4352
#define WF_BE2  4416
#define WF_W3   4480
#define WF_B3   4544
#define WF_TOT  4545

typedef __hip_bfloat16 bf16;
typedef __attribute__((ext_vector_type(8))) short sh8;   // 8 bf16 (MFMA A/B frag)
typedef __attribute__((ext_vector_type(4))) float f4v;   // MFMA C/D frag

__device__ __forceinline__ float b2f(bf16 x) { return __bfloat162float(x); }
__device__ __forceinline__ unsigned short f2bs(float f) {
    union { bf16 b; unsigned short s; } u;
    u.b = __float2bfloat16(f);
    return u.s;
}
__device__ __forceinline__ float bu2f(unsigned int lo16) {   // bf16 bits -> f32
    return __uint_as_float(lo16 << 16);
}
__device__ __forceinline__ float ldf(const void* p, long i, int isf32) {
    return isf32 ? ((const float*)p)[i] : b2f(((const bf16*)p)[i]);
}

// ---------- dtype detect only ----------
__global__ void k_detect(const void* __restrict__ uE, int* __restrict__ flag) {
    const unsigned short* p = (const unsigned short*)uE;
    unsigned short v = p[2 * threadIdx.x];
    int e = (v >> 7) & 0xFF;
    unsigned long long m = __ballot(e >= 127);
    if (threadIdx.x == 0) flag[0] = (m != 0ull) ? 1 : 0;  // 1 => fp32 buffers
}

// ---------- pre: E -> transposed hi/lo planes (LDS transpose) + edge pack ----------
__global__ void __launch_bounds__(256)
k_pre(const void* __restrict__ uE, const void* __restrict__ iE,
      unsigned short* __restrict__ EtHi, unsigned short* __restrict__ EtLo,
      const int* __restrict__ rows, const int* __restrict__ cols,
      const void* __restrict__ vals,
      unsigned short* __restrict__ PkS, unsigned short* __restrict__ PkU,
      const int* __restrict__ flag) {
    __shared__ float ls[32 * 129];                    // padded: conflict-free
    int tid = threadIdx.x;
    int isf32 = flag[0];
    if (blockIdx.x < 193) {                           // node-transpose role
        int ng0 = blockIdx.x * 32;
        int nl = tid >> 3, dbase = (tid & 7) * 16;
        int node = ng0 + nl;
        #pragma unroll
        for (int i = 0; i < 16; ++i) {
            int d = dbase + i;
            float v = 0.f;
            if (node < N_CNT) {
                v = (node < U_CNT) ? ldf(uE, (long)node * D_DIM + d, isf32)
                                   : ldf(iE, (long)(node - U_CNT) * D_DIM + d, isf32);
            }
            ls[nl * 129 + d] = v;
        }
        __syncthreads();
        int nl2 = tid & 31;
        int node2 = ng0 + nl2;
        int c = (node2 < U_CNT) ? node2 : COL_S0 + (node2 - U_CNT);
        #pragma unroll
        for (int i = 0; i < 16; ++i) {
            int d = (tid >> 5) * 16 + i;
            float v = ls[nl2 * 129 + d];
            unsigned short hi = f2bs(v);
            unsigned short lo = f2bs(v - bu2f(hi));
            EtHi[d * NPAD + c] = hi;
            EtLo[d * NPAD + c] = lo;
        }
    }
    // edge packing role (all blocks)
    int e = blockIdx.x * 256 + tid;
    if (e < M_EDGE) {
        int r = rows[e];
        if (r < U_CNT) {
            int u = r, s = cols[e] - U_CNT;
            unsigned short w = f2bs(ldf(vals, e, isf32));
            int kt = u >> 5, kq = (u >> 3) & 3, j = u & 7;
            int nt = s >> 4, nn = s & 15;
            PkS[((kt * NT_S + nt) * 64 + kq * 16 + nn) * 8 + j] = w;
            int kt2 = s >> 5, kq2 = (s >> 3) & 3, j2 = s & 7;
            int nt2 = u >> 4, nn2 = u & 15;
            PkU[((kt2 * NT_U + nt2) * 64 + kq2 * 16 + nn2) * 8 + j2] = w;
        }
    }
}

// ---------- one GCN hop: MFMA GEMM with register B-reuse + split-K u-side ----------
// R13 post-mortem: FETCH 32MB/hop = B-fragments re-read 8x (once per m-tile)
// and u-side 183-deep kt chain at ~HBM latency each. Now: each wave covers
// ALL 8 m-tiles so bb is loaded once per kt and reused 8x (acc[8] = 32 VGPR,
// fits the ~88-VGPR budget); u-side splits kt 4 ways across the block's
// waves + LDS reduce (stride 33: conflict-free).
__global__ void __launch_bounds__(256)
k_hop(const unsigned short* __restrict__ EinHi, const unsigned short* __restrict__ EinLo,
      unsigned short* __restrict__ EoutHi, unsigned short* __restrict__ EoutLo,
      const unsigned short* __restrict__ PkS, const unsigned short* __restrict__ PkU) {
    __shared__ float red[4 * 64 * 33];                // 33,792 B (u-side reduce)
    int wv = threadIdx.x >> 6, lane = threadIdx.x & 63;
    int am = lane & 15, aq = lane >> 4;
    f4v acc[8];
    #pragma unroll
    for (int mt = 0; mt < 8; ++mt) acc[mt] = (f4v){0.f, 0.f, 0.f, 0.f};

    if (blockIdx.x < S_HOP_BLOCKS) {
        // ---- s-side: Eout_s^T = Et_in(u cols) @ PkS ----
        int nt = blockIdx.x * 4 + wv;
        if (nt >= NT_S) return;                       // no syncthreads on this path
        const sh8* Bp = (const sh8*)PkS;
        #pragma unroll
        for (int kt = 0; kt < KT_U; ++kt) {
            sh8 bb = Bp[(kt * NT_S + nt) * 64 + lane];
            #pragma unroll
            for (int mt = 0; mt < 8; ++mt) {
                const unsigned short* bh = EinHi + (size_t)(mt * 16 + am) * NPAD + kt * 32 + aq * 8;
                const unsigned short* bl = EinLo + (size_t)(mt * 16 + am) * NPAD + kt * 32 + aq * 8;
                sh8 ah = *(const sh8*)bh;
                sh8 al = *(const sh8*)bl;
                acc[mt] = __builtin_amdgcn_mfma_f32_16x16x32_bf16(ah, bb, acc[mt], 0, 0, 0);
                acc[mt] = __builtin_amdgcn_mfma_f32_16x16x32_bf16(al, bb, acc[mt], 0, 0, 0);
            }
        }
        int outcol = COL_S0 + nt * 16 + am;
        #pragma unroll
        for (int mt = 0; mt < 8; ++mt) {
            #pragma unroll
            for (int reg = 0; reg < 4; ++reg) {
                int d = mt * 16 + aq * 4 + reg;
                float v = acc[mt][reg];
                unsigned short hi = f2bs(v);
                unsigned short lo = f2bs(v - bu2f(hi));
                EoutHi[(size_t)d * NPAD + outcol] = hi;
                EoutLo[(size_t)d * NPAD + outcol] = lo;
            }
        }
    } else {
        // ---- u-side: Eout_u^T = Et_in(s cols) @ PkU, split-K x4 ----
        int nt = blockIdx.x - S_HOP_BLOCKS;           // 0..21
        int k0 = wv * U_KCHUNK, k1 = min(KT_S, k0 + U_KCHUNK);
        const sh8* Bp = (const sh8*)PkU;
        for (int kt = k0; kt < k1; ++kt) {
            sh8 bb = Bp[(kt * NT_U + nt) * 64 + lane];
            #pragma unroll
            for (int mt = 0; mt < 8; ++mt) {
                const unsigned short* bh = EinHi + (size_t)(mt * 16 + am) * NPAD + COL_S0 + kt * 32 + aq * 8;
                const unsigned short* bl = EinLo + (size_t)(mt * 16 + am) * NPAD + COL_S0 + kt * 32 + aq * 8;
                sh8 ah = *(const sh8*)bh;
                sh8 al = *(const sh8*)bl;
                acc[mt] = __builtin_amdgcn_mfma_f32_16x16x32_bf16(ah, bb, acc[mt], 0, 0, 0);
                acc[mt] = __builtin_amdgcn_mfma_f32_16x16x32_bf16(al, bb, acc[mt], 0, 0, 0);
            }
        }
        float* my = red + (wv * 64 + lane) * 33;
        #pragma unroll
        for (int mt = 0; mt < 8; ++mt)
            #pragma unroll
            for (int reg = 0; reg < 4; ++reg) my[mt * 4 + reg] = acc[mt][reg];
        __syncthreads();
        if (wv == 0) {
            int outcol = nt * 16 + am;
            #pragma unroll
            for (int mt = 0; mt < 8; ++mt) {
                #pragma unroll
                for (int reg = 0; reg < 4; ++reg) {
                    int i = mt * 4 + reg;
                    float v = red[(0 * 64 + lane) * 33 + i] + red[(1 * 64 + lane) * 33 + i]
                            + red[(2 * 64 + lane) * 33 + i] + red[(3 * 64 + lane) * 33 + i];
                    int d = mt * 16 + aq * 4 + reg;
                    unsigned short hi = f2bs(v);
                    unsigned short lo = f2bs(v - bu2f(hi));
                    EoutHi[(size_t)d * NPAD + outcol] = hi;
                    EoutLo[(size_t)d * NPAD + outcol] = lo;
                }
            }
        }
    }
}

// ---------- hyperP: blocks 0..7 = P col-slices; block 8 = weight prep ----------
__global__ void __launch_bounds__(256)
k_hyperP(const void* __restrict__ uHy, const void* __restrict__ iHy,
         const void* __restrict__ W1, const void* __restrict__ W2,
         const void* __restrict__ b1, const void* __restrict__ g1,
         const void* __restrict__ be1, const void* __restrict__ b2,
         const void* __restrict__ g2, const void* __restrict__ be2,
         const void* __restrict__ W3, const void* __restrict__ b3,
         float* __restrict__ P, float* __restrict__ Wf,
         unsigned short* __restrict__ Wb,
         const int* __restrict__ flag) {
    int isf32 = flag[0];
    int tid = threadIdx.x;
    if (blockIdx.x == 8) {                            // weight prep
        for (int i = tid; i < 4096; i += 256) {
            int j = i & 7, lane = (i >> 3) & 63, kh = (i >> 9) & 1, t = i >> 10;
            int k = kh * 32 + ((lane >> 4) & 3) * 8 + j;
            int n = t * 16 + (lane & 15);
            Wb[i] = f2bs(ldf(W2, k * 64 + n, isf32));
        }
        for (int i = tid; i < WF_TOT - 4096; i += 256) {
            int g = 4096 + i;
            float v;
            if      (g < WF_G1)  v = ldf(b1,  g - WF_B1,   isf32);
            else if (g < WF_BE1) v = ldf(g1,  g - WF_G1,   isf32);
            else if (g < WF_B2)  v = ldf(be1, g - WF_BE1,  isf32);
            else if (g < WF_G2)  v = ldf(b2,  g - WF_B2,   isf32);
            else if (g < WF_BE2) v = ldf(g2,  g - WF_G2,   isf32);
            else if (g < WF_W3)  v = ldf(be2, g - WF_BE2,  isf32);
            else if (g < WF_B3)  v = ldf(W3,  g - WF_W3,   isf32);
            else                 v = ldf(b3,  0,           isf32);
            Wf[g] = v;
        }
        return;
    }
    int side = blockIdx.x >> 2;                       // 0 = user, 1 = service
    int j0 = (blockIdx.x & 3) * 16;                   // 16 P-columns per block
    const void* Hy = side ? iHy : uHy;                // [32][128]
    long wbase = (long)side * D_DIM * H_DIM;
    __shared__ float Hs[R_DIM * 129];
    __shared__ float Ws[D_DIM * 16];
    __shared__ float Ts[R_DIM * 16];
    if (isf32) {
        const float* H = (const float*)Hy;
        for (int i = tid; i < R_DIM * D_DIM; i += 256)
            Hs[(i >> 7) * 129 + (i & 127)] = H[i];
        const float* Wp = (const float*)W1 + wbase;
        for (int i = tid; i < D_DIM * 16; i += 256)
            Ws[i] = Wp[(i >> 4) * H_DIM + j0 + (i & 15)];
    } else {
        const unsigned short* H = (const unsigned short*)Hy;
        for (int i = tid; i < R_DIM * D_DIM; i += 256)
            Hs[(i >> 7) * 129 + (i & 127)] = bu2f(H[i]);
        const unsigned short* Wp = (const unsigned short*)W1 + wbase;
        for (int i = tid; i < D_DIM * 16; i += 256)
            Ws[i] = bu2f(Wp[(i >> 4) * H_DIM + j0 + (i & 15)]);
    }
    __syncthreads();
    for (int idx = tid; idx < R_DIM * 16; idx += 256) {
        int a = idx >> 4, j = idx & 15;
        float acc = 0.f;
        #pragma unroll 8
        for (int d = 0; d < D_DIM; ++d)
            acc = fmaf(Hs[a * 129 + d], Ws[d * 16 + j], acc);
        Ts[idx] = acc;
    }
    __syncthreads();
    for (int idx = tid; idx < D_DIM * 16; idx += 256) {
        int d = idx >> 4, j = idx & 15;
        float acc = 0.f;
        #pragma unroll
        for (int a = 0; a < R_DIM; ++a)
            acc = fmaf(Hs[a * 129 + d], Ts[a * 16 + j], acc);
        P[side * D_DIM * H_DIM + d * H_DIM + j0 + j] = acc;
    }
}

// ---------- A[r,:] = E[r,:] @ P(side) (+ b1), reading transposed hi/lo E ----------
__global__ void k_A(const unsigned short* __restrict__ EtHi,
                    const unsigned short* __restrict__ EtLo,
                    const float* __restrict__ P, const float* __restrict__ Wf,
                    float* __restrict__ A) {
    int r = blockIdx.x;
    int j = threadIdx.x;                              // 64 threads
    int c = (r < U_CNT) ? r : COL_S0 + (r - U_CNT);
    const float* Pr = P + ((r < U_CNT) ? 0 : D_DIM * H_DIM);
    float acc = (r < U_CNT) ? Wf[WF_B1 + j] : 0.f;
    #pragma unroll 8
    for (int d = 0; d < D_DIM; ++d) {
        float e = bu2f(EtHi[(size_t)d * NPAD + c]) + bu2f(EtLo[(size_t)d * NPAD + c]);
        acc = fmaf(e, Pr[d * H_DIM + j], acc);
    }
    A[r * H_DIM + j] = acc;
}

// ---------- fused MLP via MFMA (R9-verified, unchanged) ----------
__global__ void __launch_bounds__(256)
HyperModel_65755949301857_kernel(
      const float* __restrict__ A, const int* __restrict__ userIdx,
      const int* __restrict__ servIdx, const float* __restrict__ Wf,
      const unsigned short* __restrict__ Wb,
      void* __restrict__ out, const int* __restrict__ flag) {
    int tid = threadIdx.x;
    int wave = tid >> 6, lane = tid & 63;
    long b0 = ((long)blockIdx.x * 4 + wave) * 16;
    if (b0 >= B_CNT) return;
    int isf32 = flag[0];
    int m = lane & 15, quad = lane >> 4;

    int r = (int)b0 + m;
    int ui = userIdx[r];
    int si = servIdx[r] + U_CNT;
    const float* Aur = A + (long)ui * 64;
    const float* Asr = A + (long)si * 64;

    float4 ul0 = *(const float4*)(Aur + quad * 8);
    float4 ul1 = *(const float4*)(Aur + quad * 8 + 4);
    float4 uh0 = *(const float4*)(Aur + 32 + quad * 8);
    float4 uh1 = *(const float4*)(Aur + 32 + quad * 8 + 4);
    float4 sl0 = *(const float4*)(Asr + quad * 8);
    float4 sl1 = *(const float4*)(Asr + quad * 8 + 4);
    float4 sh0 = *(const float4*)(Asr + 32 + quad * 8);
    float4 sh1 = *(const float4*)(Asr + 32 + quad * 8 + 4);
    float zl[8], zh[8];
    zl[0] = ul0.x + sl0.x; zl[1] = ul0.y + sl0.y; zl[2] = ul0.z + sl0.z; zl[3] = ul0.w + sl0.w;
    zl[4] = ul1.x + sl1.x; zl[5] = ul1.y + sl1.y; zl[6] = ul1.z + sl1.z; zl[7] = ul1.w + sl1.w;
    zh[0] = uh0.x + sh0.x; zh[1] = uh0.y + sh0.y; zh[2] = uh0.z + sh0.z; zh[3] = uh0.w + sh0.w;
    zh[4] = uh1.x + sh1.x; zh[5] = uh1.y + sh1.y; zh[6] = uh1.z + sh1.z; zh[7] = uh1.w + sh1.w;

    float s = 0.f, q = 0.f;
    #pragma unroll
    for (int j = 0; j < 8; ++j) {
        s += zl[j] + zh[j];
        q = fmaf(zl[j], zl[j], q);
        q = fmaf(zh[j], zh[j], q);
    }
    s += __shfl_xor(s, 16, 64); s += __shfl_xor(s, 32, 64);
    q += __shfl_xor(q, 16, 64); q += __shfl_xor(q, 32, 64);
    float mu = s * (1.f / 64.f);
    float rs = rsqrtf(q * (1.f / 64.f) - mu * mu + LN_EPS);
    float nm = -mu * rs;

    const float* G1l = Wf + WF_G1 + quad * 8;
    const float* BE1l = Wf + WF_BE1 + quad * 8;
    sh8 a0, a1;
    #pragma unroll
    for (int j = 0; j < 8; ++j) {
        float h0 = fmaxf(fmaf(fmaf(zl[j], rs, nm), G1l[j],      BE1l[j]),      0.f);
        float h1 = fmaxf(fmaf(fmaf(zh[j], rs, nm), G1l[32 + j], BE1l[32 + j]), 0.f);
        a0[j] = (short)f2bs(h0);
        a1[j] = (short)f2bs(h1);
    }

    const sh8* Bp = (const sh8*)Wb;
    sh8 b00 = Bp[0 * 64 + lane], b01 = Bp[1 * 64 + lane];
    sh8 b10 = Bp[2 * 64 + lane], b11 = Bp[3 * 64 + lane];
    sh8 b20 = Bp[4 * 64 + lane], b21 = Bp[5 * 64 + lane];
    sh8 b30 = Bp[6 * 64 + lane], b31 = Bp[7 * 64 + lane];
    f4v acc0 = {0.f, 0.f, 0.f, 0.f}, acc1 = acc0, acc2 = acc0, acc3 = acc0;
    acc0 = __builtin_amdgcn_mfma_f32_16x16x32_bf16(a0, b00, acc0, 0, 0, 0);
    acc0 = __builtin_amdgcn_mfma_f32_16x16x32_bf16(a1, b01, acc0, 0, 0, 0);
    acc1 = __builtin_amdgcn_mfma_f32_16x16x32_bf16(a0, b10, acc1, 0, 0, 0);
    acc1 = __builtin_amdgcn_mfma_f32_16x16x32_bf16(a1, b11, acc1, 0, 0, 0);
    acc2 = __builtin_amdgcn_mfma_f32_16x16x32_bf16(a0, b20, acc2, 0, 0, 0);
    acc2 = __builtin_amdgcn_mfma_f32_16x16x32_bf16(a1, b21, acc2, 0, 0, 0);
    acc3 = __builtin_amdgcn_mfma_f32_16x16x32_bf16(a0, b30, acc3, 0, 0, 0);
    acc3 = __builtin_amdgcn_mfma_f32_16x16x32_bf16(a1, b31, acc3, 0, 0, 0);

    float b2c0 = Wf[WF_B2 + 0 * 16 + m], b2c1 = Wf[WF_B2 + 1 * 16 + m];
    float b2c2 = Wf[WF_B2 + 2 * 16 + m], b2c3 = Wf[WF_B2 + 3 * 16 + m];
    float y0[4], y1[4], y2[4], y3[4];
    float srow[4], qrow[4];
    #pragma unroll
    for (int reg = 0; reg < 4; ++reg) {
        y0[reg] = acc0[reg] + b2c0;
        y1[reg] = acc1[reg] + b2c1;
        y2[reg] = acc2[reg] + b2c2;
        y3[reg] = acc3[reg] + b2c3;
        srow[reg] = (y0[reg] + y1[reg]) + (y2[reg] + y3[reg]);
        float qa = y0[reg] * y0[reg];
        qa = fmaf(y1[reg], y1[reg], qa);
        qa = fmaf(y2[reg], y2[reg], qa);
        qa = fmaf(y3[reg], y3[reg], qa);
        qrow[reg] = qa;
    }
    #pragma unroll
    for (int off = 1; off < 16; off <<= 1) {
        #pragma unroll
        for (int reg = 0; reg < 4; ++reg) {
            srow[reg] += __shfl_xor(srow[reg], off, 64);
            qrow[reg] += __shfl_xor(qrow[reg], off, 64);
        }
    }

    float g2c0 = Wf[WF_G2 + m],      g2c1 = Wf[WF_G2 + 16 + m];
    float g2c2 = Wf[WF_G2 + 32 + m], g2c3 = Wf[WF_G2 + 48 + m];
    float e2c0 = Wf[WF_BE2 + m],      e2c1 = Wf[WF_BE2 + 16 + m];
    float e2c2 = Wf[WF_BE2 + 32 + m], e2c3 = Wf[WF_BE2 + 48 + m];
    float w3c0 = Wf[WF_W3 + m],      w3c1 = Wf[WF_W3 + 16 + m];
    float w3c2 = Wf[WF_W3 + 32 + m], w3c3 = Wf[WF_W3 + 48 + m];
    float b3v = Wf[WF_B3];
    float o[4];
    #pragma unroll
    for (int reg = 0; reg < 4; ++reg) {
        float mu2 = srow[reg] * (1.f / 64.f);
        float rs2 = rsqrtf(qrow[reg] * (1.f / 64.f) - mu2 * mu2 + LN_EPS);
        float nm2 = -mu2 * rs2;
        float t0 = fmaxf(fmaf(fmaf(y0[reg], rs2, nm2), g2c0, e2c0), 0.f);
        float t1 = fmaxf(fmaf(fmaf(y1[reg], rs2, nm2), g2c1, e2c1), 0.f);
        float t2 = fmaxf(fmaf(fmaf(y2[reg], rs2, nm2), g2c2, e2c2), 0.f);
        float t3 = fmaxf(fmaf(fmaf(y3[reg], rs2, nm2), g2c3, e2c3), 0.f);
        o[reg] = fmaf(t0, w3c0, fmaf(t1, w3c1, fmaf(t2, w3c2, t3 * w3c3)));
    }
    #pragma unroll
    for (int off = 1; off < 16; off <<= 1) {
        #pragma unroll
        for (int reg = 0; reg < 4; ++reg) o[reg] += __shfl_xor(o[reg], off, 64);
    }
    if (m == 0) {
        long rb = b0 + quad * 4;
        if (isf32) {
            float4 v = make_float4(o[0] + b3v, o[1] + b3v, o[2] + b3v, o[3] + b3v);
            *(float4*)((float*)out + rb) = v;
        } else {
            ushort4 v;
            v.x = f2bs(o[0] + b3v);
            v.y = f2bs(o[1] + b3v);
            v.z = f2bs(o[2] + b3v);
            v.w = f2bs(o[3] + b3v);
            *(ushort4*)((bf16*)out + rb) = v;
        }
    }
}

extern "C" __attribute__((visibility("default")))
void kernel_launch(void* const* d_in, const int* in_sizes, int n_in,
                   void* d_out, int out_size, void* d_ws, size_t ws_size,
                   hipStream_t stream) {
    const void* uE   = d_in[0];
    const void* iE   = d_in[1];
    const void* uHy  = d_in[2];
    const void* iHy  = d_in[3];
    const void* W1   = d_in[4];
    const void* b1   = d_in[5];
    const void* g1   = d_in[6];
    const void* be1  = d_in[7];
    const void* W2   = d_in[8];
    const void* b2   = d_in[9];
    const void* g2   = d_in[10];
    const void* be2  = d_in[11];
    const void* W3   = d_in[12];
    const void* b3   = d_in[13];
    const void* adj_vals = d_in[14];
    const int*  adj_rows = (const int*)d_in[15];
    const int*  adj_cols = (const int*)d_in[16];
    const int*  userIdx  = (const int*)d_in[17];
    const int*  servIdx  = (const int*)d_in[18];

    char* w = (char*)d_ws;
    size_t off = 0;
    auto alloc = [&](size_t bytes) -> char* {
        char* p = w + off;
        off += (bytes + 255) & ~(size_t)255;
        return p;
    };
    unsigned short* E0Hi = (unsigned short*)alloc((size_t)ET_U16 * 2);
    unsigned short* E0Lo = (unsigned short*)alloc((size_t)ET_U16 * 2);
    unsigned short* E1Hi = (unsigned short*)alloc((size_t)ET_U16 * 2);
    unsigned short* E1Lo = (unsigned short*)alloc((size_t)ET_U16 * 2);
    unsigned short* PkS  = (unsigned short*)alloc((size_t)PKS_U16 * 2);
    unsigned short* PkU  = (unsigned short*)alloc((size_t)PKU_U16 * 2);
    float* P    = (float*)alloc((size_t)2 * D_DIM * H_DIM * 4);
    float* A    = (float*)alloc((size_t)N_CNT * H_DIM * 4);
    int*   flag = (int*)alloc(256);
    float* Wf   = (float*)alloc((size_t)WF_TOT * 4);
    unsigned short* Wb = (unsigned short*)alloc((size_t)4096 * 2);

    k_detect<<<1, 64, 0, stream>>>(uE, flag);
    hipMemsetAsync(PkS, 0, (size_t)PKS_U16 * 2, stream);
    hipMemsetAsync(PkU, 0, (size_t)PKU_U16 * 2, stream);
    k_pre<<<(M_EDGE + 255) / 256, 256, 0, stream>>>(uE, iE, E0Hi, E0Lo,
                                                    adj_rows, adj_cols, adj_vals,
                                                    PkS, PkU, flag);
    // 3 hops: E0 -> E1 -> E0 -> E1 (MFMA GEMM, register B-reuse + split-K)
    k_hop<<<HOP_BLOCKS, 256, 0, stream>>>(E0Hi, E0Lo, E1Hi, E1Lo, PkS, PkU);
    k_hop<<<HOP_BLOCKS, 256, 0, stream>>>(E1Hi, E1Lo, E0Hi, E0Lo, PkS, PkU);
    k_hop<<<HOP_BLOCKS, 256, 0, stream>>>(E0Hi, E0Lo, E1Hi, E1Lo, PkS, PkU);

    k_hyperP<<<9, 256, 0, stream>>>(uHy, iHy, W1, W2, b1, g1, be1, b2, g2, be2, W3, b3,
                                    P, Wf, Wb, flag);
    k_A<<<N_CNT, H_DIM, 0, stream>>>(E1Hi, E1Lo, P, Wf, A);

    int nwaves = B_CNT / 16;                          // 31250
    HyperModel_65755949301857_kernel<<<(nwaves + 3) / 4, 256, 0, stream>>>(
        A, userIdx, servIdx, Wf, Wb, d_out, flag);
}

// Round 15
// 258.151 us; speedup vs baseline: 1.9957x; 1.9957x over previous
//
#include <hip/hip_runtime.h>
#include <hip/hip_bf16.h>

#define U_CNT 339
#define S_CNT 5825
#define N_CNT 6164          // U + S
#define D_DIM 128
#define R_DIM 32
#define B_CNT 500000
#define M_EDGE 400000       // 2*NNZ (symmetrized)
#define H_DIM 64
#define LN_EPS 1e-5f

// ---- transposed E layout: Et[d][col], col(u)=u (0..351 pad), col(s)=352+s ----
#define NPAD 6208           // 352 (u pad) + 5856 (s pad)
#define COL_S0 352
#define ET_U16 (128 * NPAD) // ushorts per plane

// ---- adjacency packed as MFMA B-fragments (bf16) ----
#define KT_U 11             // u as K: 352/32
#define KT_S 183            // s as K: 5856/32
#define NT_S 365            // s as N: 5840/16
#define NT_U 22             // u as N: 352/16
#define PKS_U16 (KT_U * NT_S * 512)   // B[k=u][n=s]
#define PKU_U16 (KT_S * NT_U * 512)   // B[k=s][n=u]

// hop grid: 512-thread blocks.
// s-side: block per nt (365), 8 waves = 8 m-tiles (R13's proven 11-kt chains).
// u-side: block per (nt,mt) (176), 8-way split-K (23 kt/wave) + LDS reduce.
#define S_HOP_BLOCKS NT_S                 // 365
#define U_HOP_BLOCKS (NT_U * 8)           // 176
#define HOP_BLOCKS (S_HOP_BLOCKS + U_HOP_BLOCKS)   // 541
#define U_KCHUNK 23                        // 8*23 = 184 >= 183

// fp32 weight-block offsets (elements)
#define WF_B1   4096
#define WF_G1   4160
#define WF_BE1  4224
#define WF_B2   4288
#define WF_G2   4352
#define WF_BE2  4416
#define WF_W3   4480
#define WF_B3   4544
#define WF_TOT  4545

typedef __hip_bfloat16 bf16;
typedef __attribute__((ext_vector_type(8))) short sh8;   // 8 bf16 (MFMA A/B frag)
typedef __attribute__((ext_vector_type(4))) float f4v;   // MFMA C/D frag

__device__ __forceinline__ float b2f(bf16 x) { return __bfloat162float(x); }
__device__ __forceinline__ unsigned short f2bs(float f) {
    union { bf16 b; unsigned short s; } u;
    u.b = __float2bfloat16(f);
    return u.s;
}
__device__ __forceinline__ float bu2f(unsigned int lo16) {   // bf16 bits -> f32
    return __uint_as_float(lo16 << 16);
}
__device__ __forceinline__ float ldf(const void* p, long i, int isf32) {
    return isf32 ? ((const float*)p)[i] : b2f(((const bf16*)p)[i]);
}

// ---------- dtype detect only ----------
__global__ void k_detect(const void* __restrict__ uE, int* __restrict__ flag) {
    const unsigned short* p = (const unsigned short*)uE;
    unsigned short v = p[2 * threadIdx.x];
    int e = (v >> 7) & 0xFF;
    unsigned long long m = __ballot(e >= 127);
    if (threadIdx.x == 0) flag[0] = (m != 0ull) ? 1 : 0;  // 1 => fp32 buffers
}

// ---------- pre: E -> transposed hi/lo planes (LDS transpose) + edge pack ----------
__global__ void __launch_bounds__(256)
k_pre(const void* __restrict__ uE, const void* __restrict__ iE,
      unsigned short* __restrict__ EtHi, unsigned short* __restrict__ EtLo,
      const int* __restrict__ rows, const int* __restrict__ cols,
      const void* __restrict__ vals,
      unsigned short* __restrict__ PkS, unsigned short* __restrict__ PkU,
      const int* __restrict__ flag) {
    __shared__ float ls[32 * 129];                    // padded: conflict-free
    int tid = threadIdx.x;
    int isf32 = flag[0];
    if (blockIdx.x < 193) {                           // node-transpose role
        int ng0 = blockIdx.x * 32;
        int nl = tid >> 3, dbase = (tid & 7) * 16;
        int node = ng0 + nl;
        #pragma unroll
        for (int i = 0; i < 16; ++i) {
            int d = dbase + i;
            float v = 0.f;
            if (node < N_CNT) {
                v = (node < U_CNT) ? ldf(uE, (long)node * D_DIM + d, isf32)
                                   : ldf(iE, (long)(node - U_CNT) * D_DIM + d, isf32);
            }
            ls[nl * 129 + d] = v;
        }
        __syncthreads();
        int nl2 = tid & 31;
        int node2 = ng0 + nl2;
        int c = (node2 < U_CNT) ? node2 : COL_S0 + (node2 - U_CNT);
        #pragma unroll
        for (int i = 0; i < 16; ++i) {
            int d = (tid >> 5) * 16 + i;
            float v = ls[nl2 * 129 + d];
            unsigned short hi = f2bs(v);
            unsigned short lo = f2bs(v - bu2f(hi));
            EtHi[d * NPAD + c] = hi;
            EtLo[d * NPAD + c] = lo;
        }
    }
    // edge packing role (all blocks)
    int e = blockIdx.x * 256 + tid;
    if (e < M_EDGE) {
        int r = rows[e];
        if (r < U_CNT) {
            int u = r, s = cols[e] - U_CNT;
            unsigned short w = f2bs(ldf(vals, e, isf32));
            int kt = u >> 5, kq = (u >> 3) & 3, j = u & 7;
            int nt = s >> 4, nn = s & 15;
            PkS[((kt * NT_S + nt) * 64 + kq * 16 + nn) * 8 + j] = w;
            int kt2 = s >> 5, kq2 = (s >> 3) & 3, j2 = s & 7;
            int nt2 = u >> 4, nn2 = u & 15;
            PkU[((kt2 * NT_U + nt2) * 64 + kq2 * 16 + nn2) * 8 + j2] = w;
        }
    }
}

// ---------- one GCN hop: MFMA GEMM ----------
// R14 post-mortem: 114-block grid starved the chip (occ 1.9%). R15: back to
// one (mt,nt) tile per wave on the s-side (2920 waves, 11-kt chains) and the
// u-side's 183-kt chain split 8 ways inside a 512-thread block (1408 waves,
// 23-kt chains) + float4 LDS reduce (b128, 2-way aliasing = free).
__global__ void __launch_bounds__(512)
k_hop(const unsigned short* __restrict__ EinHi, const unsigned short* __restrict__ EinLo,
      unsigned short* __restrict__ EoutHi, unsigned short* __restrict__ EoutLo,
      const unsigned short* __restrict__ PkS, const unsigned short* __restrict__ PkU) {
    __shared__ float4 red[512];                       // 8 KB (u-side reduce)
    int wv = threadIdx.x >> 6, lane = threadIdx.x & 63;
    int am = lane & 15, aq = lane >> 4;
    f4v acc = {0.f, 0.f, 0.f, 0.f};

    if (blockIdx.x < S_HOP_BLOCKS) {
        // ---- s-side: block = nt, wave = m-tile ----
        int nt = blockIdx.x;
        int mt = wv;
        const sh8* Bp = (const sh8*)PkS;
        const unsigned short* rowH = EinHi + (size_t)(mt * 16 + am) * NPAD;
        const unsigned short* rowL = EinLo + (size_t)(mt * 16 + am) * NPAD;
        #pragma unroll
        for (int kt = 0; kt < KT_U; ++kt) {
            sh8 bb = Bp[(kt * NT_S + nt) * 64 + lane];
            sh8 ah = *(const sh8*)(rowH + kt * 32 + aq * 8);
            sh8 al = *(const sh8*)(rowL + kt * 32 + aq * 8);
            acc = __builtin_amdgcn_mfma_f32_16x16x32_bf16(ah, bb, acc, 0, 0, 0);
            acc = __builtin_amdgcn_mfma_f32_16x16x32_bf16(al, bb, acc, 0, 0, 0);
        }
        int outcol = COL_S0 + nt * 16 + am;
        #pragma unroll
        for (int reg = 0; reg < 4; ++reg) {
            int d = mt * 16 + aq * 4 + reg;
            float v = acc[reg];
            unsigned short hi = f2bs(v);
            unsigned short lo = f2bs(v - bu2f(hi));
            EoutHi[(size_t)d * NPAD + outcol] = hi;
            EoutLo[(size_t)d * NPAD + outcol] = lo;
        }
    } else {
        // ---- u-side: block = (nt, mt), 8-way split-K across waves ----
        int bid = blockIdx.x - S_HOP_BLOCKS;          // 0..175
        int nt = bid >> 3;                            // 0..21
        int mt = bid & 7;
        int k0 = wv * U_KCHUNK, k1 = min(KT_S, k0 + U_KCHUNK);
        const sh8* Bp = (const sh8*)PkU;
        const unsigned short* rowH = EinHi + (size_t)(mt * 16 + am) * NPAD + COL_S0;
        const unsigned short* rowL = EinLo + (size_t)(mt * 16 + am) * NPAD + COL_S0;
        for (int kt = k0; kt < k1; ++kt) {
            sh8 bb = Bp[(kt * NT_U + nt) * 64 + lane];
            sh8 ah = *(const sh8*)(rowH + kt * 32 + aq * 8);
            sh8 al = *(const sh8*)(rowL + kt * 32 + aq * 8);
            acc = __builtin_amdgcn_mfma_f32_16x16x32_bf16(ah, bb, acc, 0, 0, 0);
            acc = __builtin_amdgcn_mfma_f32_16x16x32_bf16(al, bb, acc, 0, 0, 0);
        }
        red[wv * 64 + lane] = make_float4(acc[0], acc[1], acc[2], acc[3]);
        __syncthreads();
        if (wv == 0) {
            float4 v = red[lane];
            #pragma unroll
            for (int w2 = 1; w2 < 8; ++w2) {
                float4 p = red[w2 * 64 + lane];
                v.x += p.x; v.y += p.y; v.z += p.z; v.w += p.w;
            }
            int outcol = nt * 16 + am;
            float vr[4] = {v.x, v.y, v.z, v.w};
            #pragma unroll
            for (int reg = 0; reg < 4; ++reg) {
                int d = mt * 16 + aq * 4 + reg;
                unsigned short hi = f2bs(vr[reg]);
                unsigned short lo = f2bs(vr[reg] - bu2f(hi));
                EoutHi[(size_t)d * NPAD + outcol] = hi;
                EoutLo[(size_t)d * NPAD + outcol] = lo;
            }
        }
    }
}

// ---------- hyperP: blocks 0..7 = P col-slices; block 8 = weight prep ----------
__global__ void __launch_bounds__(256)
k_hyperP(const void* __restrict__ uHy, const void* __restrict__ iHy,
         const void* __restrict__ W1, const void* __restrict__ W2,
         const void* __restrict__ b1, const void* __restrict__ g1,
         const void* __restrict__ be1, const void* __restrict__ b2,
         const void* __restrict__ g2, const void* __restrict__ be2,
         const void* __restrict__ W3, const void* __restrict__ b3,
         float* __restrict__ P, float* __restrict__ Wf,
         unsigned short* __restrict__ Wb,
         const int* __restrict__ flag) {
    int isf32 = flag[0];
    int tid = threadIdx.x;
    if (blockIdx.x == 8) {                            // weight prep
        for (int i = tid; i < 4096; i += 256) {
            int j = i & 7, lane = (i >> 3) & 63, kh = (i >> 9) & 1, t = i >> 10;
            int k = kh * 32 + ((lane >> 4) & 3) * 8 + j;
            int n = t * 16 + (lane & 15);
            Wb[i] = f2bs(ldf(W2, k * 64 + n, isf32));
        }
        for (int i = tid; i < WF_TOT - 4096; i += 256) {
            int g = 4096 + i;
            float v;
            if      (g < WF_G1)  v = ldf(b1,  g - WF_B1,   isf32);
            else if (g < WF_BE1) v = ldf(g1,  g - WF_G1,   isf32);
            else if (g < WF_B2)  v = ldf(be1, g - WF_BE1,  isf32);
            else if (g < WF_G2)  v = ldf(b2,  g - WF_B2,   isf32);
            else if (g < WF_BE2) v = ldf(g2,  g - WF_G2,   isf32);
            else if (g < WF_W3)  v = ldf(be2, g - WF_BE2,  isf32);
            else if (g < WF_B3)  v = ldf(W3,  g - WF_W3,   isf32);
            else                 v = ldf(b3,  0,           isf32);
            Wf[g] = v;
        }
        return;
    }
    int side = blockIdx.x >> 2;                       // 0 = user, 1 = service
    int j0 = (blockIdx.x & 3) * 16;                   // 16 P-columns per block
    const void* Hy = side ? iHy : uHy;                // [32][128]
    long wbase = (long)side * D_DIM * H_DIM;
    __shared__ float Hs[R_DIM * 129];
    __shared__ float Ws[D_DIM * 16];
    __shared__ float Ts[R_DIM * 16];
    if (isf32) {
        const float* H = (const float*)Hy;
        for (int i = tid; i < R_DIM * D_DIM; i += 256)
            Hs[(i >> 7) * 129 + (i & 127)] = H[i];
        const float* Wp = (const float*)W1 + wbase;
        for (int i = tid; i < D_DIM * 16; i += 256)
            Ws[i] = Wp[(i >> 4) * H_DIM + j0 + (i & 15)];
    } else {
        const unsigned short* H = (const unsigned short*)Hy;
        for (int i = tid; i < R_DIM * D_DIM; i += 256)
            Hs[(i >> 7) * 129 + (i & 127)] = bu2f(H[i]);
        const unsigned short* Wp = (const unsigned short*)W1 + wbase;
        for (int i = tid; i < D_DIM * 16; i += 256)
            Ws[i] = bu2f(Wp[(i >> 4) * H_DIM + j0 + (i & 15)]);
    }
    __syncthreads();
    for (int idx = tid; idx < R_DIM * 16; idx += 256) {
        int a = idx >> 4, j = idx & 15;
        float acc = 0.f;
        #pragma unroll 8
        for (int d = 0; d < D_DIM; ++d)
            acc = fmaf(Hs[a * 129 + d], Ws[d * 16 + j], acc);
        Ts[idx] = acc;
    }
    __syncthreads();
    for (int idx = tid; idx < D_DIM * 16; idx += 256) {
        int d = idx >> 4, j = idx & 15;
        float acc = 0.f;
        #pragma unroll
        for (int a = 0; a < R_DIM; ++a)
            acc = fmaf(Hs[a * 129 + d], Ts[a * 16 + j], acc);
        P[side * D_DIM * H_DIM + d * H_DIM + j0 + j] = acc;
    }
}

// ---------- A[r,:] = E[r,:] @ P(side) (+ b1), reading transposed hi/lo E ----------
__global__ void k_A(const unsigned short* __restrict__ EtHi,
                    const unsigned short* __restrict__ EtLo,
                    const float* __restrict__ P, const float* __restrict__ Wf,
                    float* __restrict__ A) {
    int r = blockIdx.x;
    int j = threadIdx.x;                              // 64 threads
    int c = (r < U_CNT) ? r : COL_S0 + (r - U_CNT);
    const float* Pr = P + ((r < U_CNT) ? 0 : D_DIM * H_DIM);
    float acc = (r < U_CNT) ? Wf[WF_B1 + j] : 0.f;
    #pragma unroll 8
    for (int d = 0; d < D_DIM; ++d) {
        float e = bu2f(EtHi[(size_t)d * NPAD + c]) + bu2f(EtLo[(size_t)d * NPAD + c]);
        acc = fmaf(e, Pr[d * H_DIM + j], acc);
    }
    A[r * H_DIM + j] = acc;
}

// ---------- fused MLP via MFMA (R9-verified, unchanged) ----------
__global__ void __launch_bounds__(256)
HyperModel_65755949301857_kernel(
      const float* __restrict__ A, const int* __restrict__ userIdx,
      const int* __restrict__ servIdx, const float* __restrict__ Wf,
      const unsigned short* __restrict__ Wb,
      void* __restrict__ out, const int* __restrict__ flag) {
    int tid = threadIdx.x;
    int wave = tid >> 6, lane = tid & 63;
    long b0 = ((long)blockIdx.x * 4 + wave) * 16;
    if (b0 >= B_CNT) return;
    int isf32 = flag[0];
    int m = lane & 15, quad = lane >> 4;

    int r = (int)b0 + m;
    int ui = userIdx[r];
    int si = servIdx[r] + U_CNT;
    const float* Aur = A + (long)ui * 64;
    const float* Asr = A + (long)si * 64;

    float4 ul0 = *(const float4*)(Aur + quad * 8);
    float4 ul1 = *(const float4*)(Aur + quad * 8 + 4);
    float4 uh0 = *(const float4*)(Aur + 32 + quad * 8);
    float4 uh1 = *(const float4*)(Aur + 32 + quad * 8 + 4);
    float4 sl0 = *(const float4*)(Asr + quad * 8);
    float4 sl1 = *(const float4*)(Asr + quad * 8 + 4);
    float4 sh0 = *(const float4*)(Asr + 32 + quad * 8);
    float4 sh1 = *(const float4*)(Asr + 32 + quad * 8 + 4);
    float zl[8], zh[8];
    zl[0] = ul0.x + sl0.x; zl[1] = ul0.y + sl0.y; zl[2] = ul0.z + sl0.z; zl[3] = ul0.w + sl0.w;
    zl[4] = ul1.x + sl1.x; zl[5] = ul1.y + sl1.y; zl[6] = ul1.z + sl1.z; zl[7] = ul1.w + sl1.w;
    zh[0] = uh0.x + sh0.x; zh[1] = uh0.y + sh0.y; zh[2] = uh0.z + sh0.z; zh[3] = uh0.w + sh0.w;
    zh[4] = uh1.x + sh1.x; zh[5] = uh1.y + sh1.y; zh[6] = uh1.z + sh1.z; zh[7] = uh1.w + sh1.w;

    float s = 0.f, q = 0.f;
    #pragma unroll
    for (int j = 0; j < 8; ++j) {
        s += zl[j] + zh[j];
        q = fmaf(zl[j], zl[j], q);
        q = fmaf(zh[j], zh[j], q);
    }
    s += __shfl_xor(s, 16, 64); s += __shfl_xor(s, 32, 64);
    q += __shfl_xor(q, 16, 64); q += __shfl_xor(q, 32, 64);
    float mu = s * (1.f / 64.f);
    float rs = rsqrtf(q * (1.f / 64.f) - mu * mu + LN_EPS);
    float nm = -mu * rs;

    const float* G1l = Wf + WF_G1 + quad * 8;
    const float* BE1l = Wf + WF_BE1 + quad * 8;
    sh8 a0, a1;
    #pragma unroll
    for (int j = 0; j < 8; ++j) {
        float h0 = fmaxf(fmaf(fmaf(zl[j], rs, nm), G1l[j],      BE1l[j]),      0.f);
        float h1 = fmaxf(fmaf(fmaf(zh[j], rs, nm), G1l[32 + j], BE1l[32 + j]), 0.f);
        a0[j] = (short)f2bs(h0);
        a1[j] = (short)f2bs(h1);
    }

    const sh8* Bp = (const sh8*)Wb;
    sh8 b00 = Bp[0 * 64 + lane], b01 = Bp[1 * 64 + lane];
    sh8 b10 = Bp[2 * 64 + lane], b11 = Bp[3 * 64 + lane];
    sh8 b20 = Bp[4 * 64 + lane], b21 = Bp[5 * 64 + lane];
    sh8 b30 = Bp[6 * 64 + lane], b31 = Bp[7 * 64 + lane];
    f4v acc0 = {0.f, 0.f, 0.f, 0.f}, acc1 = acc0, acc2 = acc0, acc3 = acc0;
    acc0 = __builtin_amdgcn_mfma_f32_16x16x32_bf16(a0, b00, acc0, 0, 0, 0);
    acc0 = __builtin_amdgcn_mfma_f32_16x16x32_bf16(a1, b01, acc0, 0, 0, 0);
    acc1 = __builtin_amdgcn_mfma_f32_16x16x32_bf16(a0, b10, acc1, 0, 0, 0);
    acc1 = __builtin_amdgcn_mfma_f32_16x16x32_bf16(a1, b11, acc1, 0, 0, 0);
    acc2 = __builtin_amdgcn_mfma_f32_16x16x32_bf16(a0, b20, acc2, 0, 0, 0);
    acc2 = __builtin_amdgcn_mfma_f32_16x16x32_bf16(a1, b21, acc2, 0, 0, 0);
    acc3 = __builtin_amdgcn_mfma_f32_16x16x32_bf16(a0, b30, acc3, 0, 0, 0);
    acc3 = __builtin_amdgcn_mfma_f32_16x16x32_bf16(a1, b31, acc3, 0, 0, 0);

    float b2c0 = Wf[WF_B2 + 0 * 16 + m], b2c1 = Wf[WF_B2 + 1 * 16 + m];
    float b2c2 = Wf[WF_B2 + 2 * 16 + m], b2c3 = Wf[WF_B2 + 3 * 16 + m];
    float y0[4], y1[4], y2[4], y3[4];
    float srow[4], qrow[4];
    #pragma unroll
    for (int reg = 0; reg < 4; ++reg) {
        y0[reg] = acc0[reg] + b2c0;
        y1[reg] = acc1[reg] + b2c1;
        y2[reg] = acc2[reg] + b2c2;
        y3[reg] = acc3[reg] + b2c3;
        srow[reg] = (y0[reg] + y1[reg]) + (y2[reg] + y3[reg]);
        float qa = y0[reg] * y0[reg];
        qa = fmaf(y1[reg], y1[reg], qa);
        qa = fmaf(y2[reg], y2[reg], qa);
        qa = fmaf(y3[reg], y3[reg], qa);
        qrow[reg] = qa;
    }
    #pragma unroll
    for (int off = 1; off < 16; off <<= 1) {
        #pragma unroll
        for (int reg = 0; reg < 4; ++reg) {
            srow[reg] += __shfl_xor(srow[reg], off, 64);
            qrow[reg] += __shfl_xor(qrow[reg], off, 64);
        }
    }

    float g2c0 = Wf[WF_G2 + m],      g2c1 = Wf[WF_G2 + 16 + m];
    float g2c2 = Wf[WF_G2 + 32 + m], g2c3 = Wf[WF_G2 + 48 + m];
    float e2c0 = Wf[WF_BE2 + m],      e2c1 = Wf[WF_BE2 + 16 + m];
    float e2c2 = Wf[WF_BE2 + 32 + m], e2c3 = Wf[WF_BE2 + 48 + m];
    float w3c0 = Wf[WF_W3 + m],      w3c1 = Wf[WF_W3 + 16 + m];
    float w3c2 = Wf[WF_W3 + 32 + m], w3c3 = Wf[WF_W3 + 48 + m];
    float b3v = Wf[WF_B3];
    float o[4];
    #pragma unroll
    for (int reg = 0; reg < 4; ++reg) {
        float mu2 = srow[reg] * (1.f / 64.f);
        float rs2 = rsqrtf(qrow[reg] * (1.f / 64.f) - mu2 * mu2 + LN_EPS);
        float nm2 = -mu2 * rs2;
        float t0 = fmaxf(fmaf(fmaf(y0[reg], rs2, nm2), g2c0, e2c0), 0.f);
        float t1 = fmaxf(fmaf(fmaf(y1[reg], rs2, nm2), g2c1, e2c1), 0.f);
        float t2 = fmaxf(fmaf(fmaf(y2[reg], rs2, nm2), g2c2, e2c2), 0.f);
        float t3 = fmaxf(fmaf(fmaf(y3[reg], rs2, nm2), g2c3, e2c3), 0.f);
        o[reg] = fmaf(t0, w3c0, fmaf(t1, w3c1, fmaf(t2, w3c2, t3 * w3c3)));
    }
    #pragma unroll
    for (int off = 1; off < 16; off <<= 1) {
        #pragma unroll
        for (int reg = 0; reg < 4; ++reg) o[reg] += __shfl_xor(o[reg], off, 64);
    }
    if (m == 0) {
        long rb = b0 + quad * 4;
        if (isf32) {
            float4 v = make_float4(o[0] + b3v, o[1] + b3v, o[2] + b3v, o[3] + b3v);
            *(float4*)((float*)out + rb) = v;
        } else {
            ushort4 v;
            v.x = f2bs(o[0] + b3v);
            v.y = f2bs(o[1] + b3v);
            v.z = f2bs(o[2] + b3v);
            v.w = f2bs(o[3] + b3v);
            *(ushort4*)((bf16*)out + rb) = v;
        }
    }
}

extern "C" __attribute__((visibility("default")))
void kernel_launch(void* const* d_in, const int* in_sizes, int n_in,
                   void* d_out, int out_size, void* d_ws, size_t ws_size,
                   hipStream_t stream) {
    const void* uE   = d_in[0];
    const void* iE   = d_in[1];
    const void* uHy  = d_in[2];
    const void* iHy  = d_in[3];
    const void* W1   = d_in[4];
    const void* b1   = d_in[5];
    const void* g1   = d_in[6];
    const void* be1  = d_in[7];
    const void* W2   = d_in[8];
    const void* b2   = d_in[9];
    const void* g2   = d_in[10];
    const void* be2  = d_in[11];
    const void* W3   = d_in[12];
    const void* b3   = d_in[13];
    const void* adj_vals = d_in[14];
    const int*  adj_rows = (const int*)d_in[15];
    const int*  adj_cols = (const int*)d_in[16];
    const int*  userIdx  = (const int*)d_in[17];
    const int*  servIdx  = (const int*)d_in[18];

    char* w = (char*)d_ws;
    size_t off = 0;
    auto alloc = [&](size_t bytes) -> char* {
        char* p = w + off;
        off += (bytes + 255) & ~(size_t)255;
        return p;
    };
    unsigned short* E0Hi = (unsigned short*)alloc((size_t)ET_U16 * 2);
    unsigned short* E0Lo = (unsigned short*)alloc((size_t)ET_U16 * 2);
    unsigned short* E1Hi = (unsigned short*)alloc((size_t)ET_U16 * 2);
    unsigned short* E1Lo = (unsigned short*)alloc((size_t)ET_U16 * 2);
    unsigned short* PkS  = (unsigned short*)alloc((size_t)PKS_U16 * 2);
    unsigned short* PkU  = (unsigned short*)alloc((size_t)PKU_U16 * 2);
    float* P    = (float*)alloc((size_t)2 * D_DIM * H_DIM * 4);
    float* A    = (float*)alloc((size_t)N_CNT * H_DIM * 4);
    int*   flag = (int*)alloc(256);
    float* Wf   = (float*)alloc((size_t)WF_TOT * 4);
    unsigned short* Wb = (unsigned short*)alloc((size_t)4096 * 2);

    k_detect<<<1, 64, 0, stream>>>(uE, flag);
    hipMemsetAsync(PkS, 0, (size_t)PKS_U16 * 2, stream);
    hipMemsetAsync(PkU, 0, (size_t)PKU_U16 * 2, stream);
    k_pre<<<(M_EDGE + 255) / 256, 256, 0, stream>>>(uE, iE, E0Hi, E0Lo,
                                                    adj_rows, adj_cols, adj_vals,
                                                    PkS, PkU, flag);
    // 3 hops: E0 -> E1 -> E0 -> E1 (MFMA GEMM)
    k_hop<<<HOP_BLOCKS, 512, 0, stream>>>(E0Hi, E0Lo, E1Hi, E1Lo, PkS, PkU);
    k_hop<<<HOP_BLOCKS, 512, 0, stream>>>(E1Hi, E1Lo, E0Hi, E0Lo, PkS, PkU);
    k_hop<<<HOP_BLOCKS, 512, 0, stream>>>(E0Hi, E0Lo, E1Hi, E1Lo, PkS, PkU);

    k_hyperP<<<9, 256, 0, stream>>>(uHy, iHy, W1, W2, b1, g1, be1, b2, g2, be2, W3, b3,
                                    P, Wf, Wb, flag);
    k_A<<<N_CNT, H_DIM, 0, stream>>>(E1Hi, E1Lo, P, Wf, A);

    int nwaves = B_CNT / 16;                          // 31250
    HyperModel_65755949301857_kernel<<<(nwaves + 3) / 4, 256, 0, stream>>>(
        A, userIdx, servIdx, Wf, Wb, d_out, flag);
}

// Round 16
// 252.885 us; speedup vs baseline: 2.0372x; 1.0208x over previous
//
#include <hip/hip_runtime.h>
#include <hip/hip_bf16.h>

#define U_CNT 339
#define S_CNT 5825
#define N_CNT 6164          // U + S
#define D_DIM 128
#define R_DIM 32
#define B_CNT 500000
#define M_EDGE 400000       // 2*NNZ (symmetrized)
#define H_DIM 64
#define LN_EPS 1e-5f

// ---- transposed E layout: Et[d][col], col(u)=u (0..351 pad), col(s)=352+s ----
#define NPAD 6208           // 352 (u pad) + 5856 (s pad)
#define COL_S0 352
#define ET_U16 (128 * NPAD) // ushorts per plane

// ---- adjacency packed as MFMA B-fragments (bf16) ----
#define KT_U 11             // u as K: 352/32
#define KT_S 183            // s as K: 5856/32
#define NT_S 365            // s as N: 5840/16
#define NT_U 22             // u as N: 352/16
#define PKS_U16 (KT_U * NT_S * 512)   // B[k=u][n=s]
#define PKU_U16 (KT_S * NT_U * 512)   // B[k=s][n=u]

// hop grid: 512-thread blocks (R15-verified).
#define S_HOP_BLOCKS NT_S                 // 365
#define U_HOP_BLOCKS (NT_U * 8)           // 176
#define HOP_BLOCKS (S_HOP_BLOCKS + U_HOP_BLOCKS)   // 541
#define U_KCHUNK 23                        // 8*23 = 184 >= 183

// fp32 weight-block offsets (elements)
#define WF_B1   4096
#define WF_G1   4160
#define WF_BE1  4224
#define WF_B2   4288
#define WF_G2   4352
#define WF_BE2  4416
#define WF_W3   4480
#define WF_B3   4544
#define WF_TOT  4545

#define MLP_BLOCKS 1024     // persistent grid: 4096 waves, ~7.6 tiles each

typedef __hip_bfloat16 bf16;
typedef __attribute__((ext_vector_type(8))) short sh8;   // 8 bf16 (MFMA A/B frag)
typedef __attribute__((ext_vector_type(4))) float f4v;   // MFMA C/D frag

__device__ __forceinline__ float b2f(bf16 x) { return __bfloat162float(x); }
__device__ __forceinline__ unsigned short f2bs(float f) {
    union { bf16 b; unsigned short s; } u;
    u.b = __float2bfloat16(f);
    return u.s;
}
__device__ __forceinline__ float bu2f(unsigned int lo16) {   // bf16 bits -> f32
    return __uint_as_float(lo16 << 16);
}
__device__ __forceinline__ float ldf(const void* p, long i, int isf32) {
    return isf32 ? ((const float*)p)[i] : b2f(((const bf16*)p)[i]);
}

// ---------- dtype detect only ----------
__global__ void k_detect(const void* __restrict__ uE, int* __restrict__ flag) {
    const unsigned short* p = (const unsigned short*)uE;
    unsigned short v = p[2 * threadIdx.x];
    int e = (v >> 7) & 0xFF;
    unsigned long long m = __ballot(e >= 127);
    if (threadIdx.x == 0) flag[0] = (m != 0ull) ? 1 : 0;  // 1 => fp32 buffers
}

// ---------- pre: E -> transposed hi/lo planes (LDS transpose) + edge pack ----------
__global__ void __launch_bounds__(256)
k_pre(const void* __restrict__ uE, const void* __restrict__ iE,
      unsigned short* __restrict__ EtHi, unsigned short* __restrict__ EtLo,
      const int* __restrict__ rows, const int* __restrict__ cols,
      const void* __restrict__ vals,
      unsigned short* __restrict__ PkS, unsigned short* __restrict__ PkU,
      const int* __restrict__ flag) {
    __shared__ float ls[32 * 129];                    // padded: conflict-free
    int tid = threadIdx.x;
    int isf32 = flag[0];
    if (blockIdx.x < 193) {                           // node-transpose role
        int ng0 = blockIdx.x * 32;
        int nl = tid >> 3, dbase = (tid & 7) * 16;
        int node = ng0 + nl;
        #pragma unroll
        for (int i = 0; i < 16; ++i) {
            int d = dbase + i;
            float v = 0.f;
            if (node < N_CNT) {
                v = (node < U_CNT) ? ldf(uE, (long)node * D_DIM + d, isf32)
                                   : ldf(iE, (long)(node - U_CNT) * D_DIM + d, isf32);
            }
            ls[nl * 129 + d] = v;
        }
        __syncthreads();
        int nl2 = tid & 31;
        int node2 = ng0 + nl2;
        int c = (node2 < U_CNT) ? node2 : COL_S0 + (node2 - U_CNT);
        #pragma unroll
        for (int i = 0; i < 16; ++i) {
            int d = (tid >> 5) * 16 + i;
            float v = ls[nl2 * 129 + d];
            unsigned short hi = f2bs(v);
            unsigned short lo = f2bs(v - bu2f(hi));
            EtHi[d * NPAD + c] = hi;
            EtLo[d * NPAD + c] = lo;
        }
    }
    // edge packing role (all blocks)
    int e = blockIdx.x * 256 + tid;
    if (e < M_EDGE) {
        int r = rows[e];
        if (r < U_CNT) {
            int u = r, s = cols[e] - U_CNT;
            unsigned short w = f2bs(ldf(vals, e, isf32));
            int kt = u >> 5, kq = (u >> 3) & 3, j = u & 7;
            int nt = s >> 4, nn = s & 15;
            PkS[((kt * NT_S + nt) * 64 + kq * 16 + nn) * 8 + j] = w;
            int kt2 = s >> 5, kq2 = (s >> 3) & 3, j2 = s & 7;
            int nt2 = u >> 4, nn2 = u & 15;
            PkU[((kt2 * NT_U + nt2) * 64 + kq2 * 16 + nn2) * 8 + j2] = w;
        }
    }
}

// ---------- one GCN hop: MFMA GEMM (R15-verified) ----------
__global__ void __launch_bounds__(512)
k_hop(const unsigned short* __restrict__ EinHi, const unsigned short* __restrict__ EinLo,
      unsigned short* __restrict__ EoutHi, unsigned short* __restrict__ EoutLo,
      const unsigned short* __restrict__ PkS, const unsigned short* __restrict__ PkU) {
    __shared__ float4 red[512];                       // 8 KB (u-side reduce)
    int wv = threadIdx.x >> 6, lane = threadIdx.x & 63;
    int am = lane & 15, aq = lane >> 4;
    f4v acc = {0.f, 0.f, 0.f, 0.f};

    if (blockIdx.x < S_HOP_BLOCKS) {
        // ---- s-side: block = nt, wave = m-tile ----
        int nt = blockIdx.x;
        int mt = wv;
        const sh8* Bp = (const sh8*)PkS;
        const unsigned short* rowH = EinHi + (size_t)(mt * 16 + am) * NPAD;
        const unsigned short* rowL = EinLo + (size_t)(mt * 16 + am) * NPAD;
        #pragma unroll
        for (int kt = 0; kt < KT_U; ++kt) {
            sh8 bb = Bp[(kt * NT_S + nt) * 64 + lane];
            sh8 ah = *(const sh8*)(rowH + kt * 32 + aq * 8);
            sh8 al = *(const sh8*)(rowL + kt * 32 + aq * 8);
            acc = __builtin_amdgcn_mfma_f32_16x16x32_bf16(ah, bb, acc, 0, 0, 0);
            acc = __builtin_amdgcn_mfma_f32_16x16x32_bf16(al, bb, acc, 0, 0, 0);
        }
        int outcol = COL_S0 + nt * 16 + am;
        #pragma unroll
        for (int reg = 0; reg < 4; ++reg) {
            int d = mt * 16 + aq * 4 + reg;
            float v = acc[reg];
            unsigned short hi = f2bs(v);
            unsigned short lo = f2bs(v - bu2f(hi));
            EoutHi[(size_t)d * NPAD + outcol] = hi;
            EoutLo[(size_t)d * NPAD + outcol] = lo;
        }
    } else {
        // ---- u-side: block = (nt, mt), 8-way split-K across waves ----
        int bid = blockIdx.x - S_HOP_BLOCKS;          // 0..175
        int nt = bid >> 3;                            // 0..21
        int mt = bid & 7;
        int k0 = wv * U_KCHUNK, k1 = min(KT_S, k0 + U_KCHUNK);
        const sh8* Bp = (const sh8*)PkU;
        const unsigned short* rowH = EinHi + (size_t)(mt * 16 + am) * NPAD + COL_S0;
        const unsigned short* rowL = EinLo + (size_t)(mt * 16 + am) * NPAD + COL_S0;
        for (int kt = k0; kt < k1; ++kt) {
            sh8 bb = Bp[(kt * NT_U + nt) * 64 + lane];
            sh8 ah = *(const sh8*)(rowH + kt * 32 + aq * 8);
            sh8 al = *(const sh8*)(rowL + kt * 32 + aq * 8);
            acc = __builtin_amdgcn_mfma_f32_16x16x32_bf16(ah, bb, acc, 0, 0, 0);
            acc = __builtin_amdgcn_mfma_f32_16x16x32_bf16(al, bb, acc, 0, 0, 0);
        }
        red[wv * 64 + lane] = make_float4(acc[0], acc[1], acc[2], acc[3]);
        __syncthreads();
        if (wv == 0) {
            float4 v = red[lane];
            #pragma unroll
            for (int w2 = 1; w2 < 8; ++w2) {
                float4 p = red[w2 * 64 + lane];
                v.x += p.x; v.y += p.y; v.z += p.z; v.w += p.w;
            }
            int outcol = nt * 16 + am;
            float vr[4] = {v.x, v.y, v.z, v.w};
            #pragma unroll
            for (int reg = 0; reg < 4; ++reg) {
                int d = mt * 16 + aq * 4 + reg;
                unsigned short hi = f2bs(vr[reg]);
                unsigned short lo = f2bs(vr[reg] - bu2f(hi));
                EoutHi[(size_t)d * NPAD + outcol] = hi;
                EoutLo[(size_t)d * NPAD + outcol] = lo;
            }
        }
    }
}

// ---------- hyperP: blocks 0..7 = P col-slices; block 8 = weight prep ----------
__global__ void __launch_bounds__(256)
k_hyperP(const void* __restrict__ uHy, const void* __restrict__ iHy,
         const void* __restrict__ W1, const void* __restrict__ W2,
         const void* __restrict__ b1, const void* __restrict__ g1,
         const void* __restrict__ be1, const void* __restrict__ b2,
         const void* __restrict__ g2, const void* __restrict__ be2,
         const void* __restrict__ W3, const void* __restrict__ b3,
         float* __restrict__ P, float* __restrict__ Wf,
         unsigned short* __restrict__ Wb,
         const int* __restrict__ flag) {
    int isf32 = flag[0];
    int tid = threadIdx.x;
    if (blockIdx.x == 8) {                            // weight prep
        for (int i = tid; i < 4096; i += 256) {
            int j = i & 7, lane = (i >> 3) & 63, kh = (i >> 9) & 1, t = i >> 10;
            int k = kh * 32 + ((lane >> 4) & 3) * 8 + j;
            int n = t * 16 + (lane & 15);
            Wb[i] = f2bs(ldf(W2, k * 64 + n, isf32));
        }
        for (int i = tid; i < WF_TOT - 4096; i += 256) {
            int g = 4096 + i;
            float v;
            if      (g < WF_G1)  v = ldf(b1,  g - WF_B1,   isf32);
            else if (g < WF_BE1) v = ldf(g1,  g - WF_G1,   isf32);
            else if (g < WF_B2)  v = ldf(be1, g - WF_BE1,  isf32);
            else if (g < WF_G2)  v = ldf(b2,  g - WF_B2,   isf32);
            else if (g < WF_BE2) v = ldf(g2,  g - WF_G2,   isf32);
            else if (g < WF_W3)  v = ldf(be2, g - WF_BE2,  isf32);
            else if (g < WF_B3)  v = ldf(W3,  g - WF_W3,   isf32);
            else                 v = ldf(b3,  0,           isf32);
            Wf[g] = v;
        }
        return;
    }
    int side = blockIdx.x >> 2;                       // 0 = user, 1 = service
    int j0 = (blockIdx.x & 3) * 16;                   // 16 P-columns per block
    const void* Hy = side ? iHy : uHy;                // [32][128]
    long wbase = (long)side * D_DIM * H_DIM;
    __shared__ float Hs[R_DIM * 129];
    __shared__ float Ws[D_DIM * 16];
    __shared__ float Ts[R_DIM * 16];
    if (isf32) {
        const float* H = (const float*)Hy;
        for (int i = tid; i < R_DIM * D_DIM; i += 256)
            Hs[(i >> 7) * 129 + (i & 127)] = H[i];
        const float* Wp = (const float*)W1 + wbase;
        for (int i = tid; i < D_DIM * 16; i += 256)
            Ws[i] = Wp[(i >> 4) * H_DIM + j0 + (i & 15)];
    } else {
        const unsigned short* H = (const unsigned short*)Hy;
        for (int i = tid; i < R_DIM * D_DIM; i += 256)
            Hs[(i >> 7) * 129 + (i & 127)] = bu2f(H[i]);
        const unsigned short* Wp = (const unsigned short*)W1 + wbase;
        for (int i = tid; i < D_DIM * 16; i += 256)
            Ws[i] = bu2f(Wp[(i >> 4) * H_DIM + j0 + (i & 15)]);
    }
    __syncthreads();
    for (int idx = tid; idx < R_DIM * 16; idx += 256) {
        int a = idx >> 4, j = idx & 15;
        float acc = 0.f;
        #pragma unroll 8
        for (int d = 0; d < D_DIM; ++d)
            acc = fmaf(Hs[a * 129 + d], Ws[d * 16 + j], acc);
        Ts[idx] = acc;
    }
    __syncthreads();
    for (int idx = tid; idx < D_DIM * 16; idx += 256) {
        int d = idx >> 4, j = idx & 15;
        float acc = 0.f;
        #pragma unroll
        for (int a = 0; a < R_DIM; ++a)
            acc = fmaf(Hs[a * 129 + d], Ts[a * 16 + j], acc);
        P[side * D_DIM * H_DIM + d * H_DIM + j0 + j] = acc;
    }
}

// ---------- A[r,:] = E[r,:] @ P(side) (+ b1), reading transposed hi/lo E ----------
__global__ void k_A(const unsigned short* __restrict__ EtHi,
                    const unsigned short* __restrict__ EtLo,
                    const float* __restrict__ P, const float* __restrict__ Wf,
                    float* __restrict__ A) {
    int r = blockIdx.x;
    int j = threadIdx.x;                              // 64 threads
    int c = (r < U_CNT) ? r : COL_S0 + (r - U_CNT);
    const float* Pr = P + ((r < U_CNT) ? 0 : D_DIM * H_DIM);
    float acc = (r < U_CNT) ? Wf[WF_B1 + j] : 0.f;
    #pragma unroll 8
    for (int d = 0; d < D_DIM; ++d) {
        float e = bu2f(EtHi[(size_t)d * NPAD + c]) + bu2f(EtLo[(size_t)d * NPAD + c]);
        acc = fmaf(e, Pr[d * H_DIM + j], acc);
    }
    A[r * H_DIM + j] = acc;
}

// ---------- fused MLP via MFMA: PERSISTENT + SOFTWARE-PIPELINED ----------
// R15 post-mortem: 55us, VALUBusy 34%, ~2800 stall cyc/tile -- per-tile idx->
// gather chain fully exposed, Wb fragments reloaded every tile. R16: grid-
// stride waves (~7.6 tiles each); Wb frags hoisted (loaded once per wave);
// while computing tile t, the 8 A-gather float4s of t+1 are in flight and
// the idx pair of t+2 is prefetched. Math identical to R15 (verified).
__global__ void __launch_bounds__(256)
HyperModel_65755949301857_kernel(
      const float* __restrict__ A, const int* __restrict__ userIdx,
      const int* __restrict__ servIdx, const float* __restrict__ Wf,
      const unsigned short* __restrict__ Wb,
      void* __restrict__ out, const int* __restrict__ flag) {
    int tid = threadIdx.x;
    int wv = tid >> 6, lane = tid & 63;
    int isf32 = flag[0];
    int m = lane & 15, quad = lane >> 4;

    // hoisted invariants
    const sh8* Bp = (const sh8*)Wb;
    sh8 b00 = Bp[0 * 64 + lane], b01 = Bp[1 * 64 + lane];
    sh8 b10 = Bp[2 * 64 + lane], b11 = Bp[3 * 64 + lane];
    sh8 b20 = Bp[4 * 64 + lane], b21 = Bp[5 * 64 + lane];
    sh8 b30 = Bp[6 * 64 + lane], b31 = Bp[7 * 64 + lane];
    float b2c0 = Wf[WF_B2 + m],      b2c1 = Wf[WF_B2 + 16 + m];
    float b2c2 = Wf[WF_B2 + 32 + m], b2c3 = Wf[WF_B2 + 48 + m];
    float g2c0 = Wf[WF_G2 + m],      g2c1 = Wf[WF_G2 + 16 + m];
    float g2c2 = Wf[WF_G2 + 32 + m], g2c3 = Wf[WF_G2 + 48 + m];
    float e2c0 = Wf[WF_BE2 + m],      e2c1 = Wf[WF_BE2 + 16 + m];
    float e2c2 = Wf[WF_BE2 + 32 + m], e2c3 = Wf[WF_BE2 + 48 + m];
    float w3c0 = Wf[WF_W3 + m],      w3c1 = Wf[WF_W3 + 16 + m];
    float w3c2 = Wf[WF_W3 + 32 + m], w3c3 = Wf[WF_W3 + 48 + m];
    float b3v = Wf[WF_B3];
    const float* G1l = Wf + WF_G1 + quad * 8;
    const float* BE1l = Wf + WF_BE1 + quad * 8;

    const long TILES = B_CNT / 16;                    // 31250
    const long stride = (long)gridDim.x * 4;
    long tile = (long)blockIdx.x * 4 + wv;
    if (tile >= TILES) return;

    // prologue: gather first tile; prefetch idx of second
    {
        int r0 = (int)(tile * 16 + m);
        int ui = userIdx[r0];
        int si = servIdx[r0] + U_CNT;
        (void)ui; (void)si;
    }
    int r0 = (int)(tile * 16 + m);
    const float4* Au = (const float4*)(A + (long)userIdx[r0] * 64);
    const float4* As = (const float4*)(A + (long)(servIdx[r0] + U_CNT) * 64);
    float4 bu0 = Au[quad * 2], bu1 = Au[quad * 2 + 1], bu2 = Au[8 + quad * 2], bu3 = Au[9 + quad * 2];
    float4 bs0 = As[quad * 2], bs1 = As[quad * 2 + 1], bs2 = As[8 + quad * 2], bs3 = As[9 + quad * 2];
    long tn = tile + stride;
    int uin = 0, sin = 0;
    if (tn < TILES) {
        int rn = (int)(tn * 16 + m);
        uin = userIdx[rn];
        sin = servIdx[rn] + U_CNT;
    }

    while (true) {
        // combine current buffers into z (frees buf for next prefetch)
        float zl[8], zh[8];
        zl[0] = bu0.x + bs0.x; zl[1] = bu0.y + bs0.y; zl[2] = bu0.z + bs0.z; zl[3] = bu0.w + bs0.w;
        zl[4] = bu1.x + bs1.x; zl[5] = bu1.y + bs1.y; zl[6] = bu1.z + bs1.z; zl[7] = bu1.w + bs1.w;
        zh[0] = bu2.x + bs2.x; zh[1] = bu2.y + bs2.y; zh[2] = bu2.z + bs2.z; zh[3] = bu2.w + bs2.w;
        zh[4] = bu3.x + bs3.x; zh[5] = bu3.y + bs3.y; zh[6] = bu3.z + bs3.z; zh[7] = bu3.w + bs3.w;

        long tcur = tile;
        bool have_next = (tn < TILES);
        if (have_next) {
            // issue next tile's gathers NOW (overlap with compute below)
            const float4* Au2 = (const float4*)(A + (long)uin * 64);
            const float4* As2 = (const float4*)(A + (long)sin * 64);
            bu0 = Au2[quad * 2]; bu1 = Au2[quad * 2 + 1]; bu2 = Au2[8 + quad * 2]; bu3 = Au2[9 + quad * 2];
            bs0 = As2[quad * 2]; bs1 = As2[quad * 2 + 1]; bs2 = As2[8 + quad * 2]; bs3 = As2[9 + quad * 2];
            long tnn = tn + stride;
            if (tnn < TILES) {
                int rnn = (int)(tnn * 16 + m);
                uin = userIdx[rnn];
                sin = servIdx[rnn] + U_CNT;
            }
            tile = tn;
            tn = tnn;
        }

        // ---- compute tile tcur (R15-verified body) ----
        float s = 0.f, q = 0.f;
        #pragma unroll
        for (int j = 0; j < 8; ++j) {
            s += zl[j] + zh[j];
            q = fmaf(zl[j], zl[j], q);
            q = fmaf(zh[j], zh[j], q);
        }
        s += __shfl_xor(s, 16, 64); s += __shfl_xor(s, 32, 64);
        q += __shfl_xor(q, 16, 64); q += __shfl_xor(q, 32, 64);
        float mu = s * (1.f / 64.f);
        float rs = rsqrtf(q * (1.f / 64.f) - mu * mu + LN_EPS);
        float nm = -mu * rs;

        sh8 a0, a1;
        #pragma unroll
        for (int j = 0; j < 8; ++j) {
            float h0 = fmaxf(fmaf(fmaf(zl[j], rs, nm), G1l[j],      BE1l[j]),      0.f);
            float h1 = fmaxf(fmaf(fmaf(zh[j], rs, nm), G1l[32 + j], BE1l[32 + j]), 0.f);
            a0[j] = (short)f2bs(h0);
            a1[j] = (short)f2bs(h1);
        }

        f4v acc0 = {0.f, 0.f, 0.f, 0.f}, acc1 = acc0, acc2 = acc0, acc3 = acc0;
        acc0 = __builtin_amdgcn_mfma_f32_16x16x32_bf16(a0, b00, acc0, 0, 0, 0);
        acc0 = __builtin_amdgcn_mfma_f32_16x16x32_bf16(a1, b01, acc0, 0, 0, 0);
        acc1 = __builtin_amdgcn_mfma_f32_16x16x32_bf16(a0, b10, acc1, 0, 0, 0);
        acc1 = __builtin_amdgcn_mfma_f32_16x16x32_bf16(a1, b11, acc1, 0, 0, 0);
        acc2 = __builtin_amdgcn_mfma_f32_16x16x32_bf16(a0, b20, acc2, 0, 0, 0);
        acc2 = __builtin_amdgcn_mfma_f32_16x16x32_bf16(a1, b21, acc2, 0, 0, 0);
        acc3 = __builtin_amdgcn_mfma_f32_16x16x32_bf16(a0, b30, acc3, 0, 0, 0);
        acc3 = __builtin_amdgcn_mfma_f32_16x16x32_bf16(a1, b31, acc3, 0, 0, 0);

        float y0[4], y1[4], y2[4], y3[4];
        float srow[4], qrow[4];
        #pragma unroll
        for (int reg = 0; reg < 4; ++reg) {
            y0[reg] = acc0[reg] + b2c0;
            y1[reg] = acc1[reg] + b2c1;
            y2[reg] = acc2[reg] + b2c2;
            y3[reg] = acc3[reg] + b2c3;
            srow[reg] = (y0[reg] + y1[reg]) + (y2[reg] + y3[reg]);
            float qa = y0[reg] * y0[reg];
            qa = fmaf(y1[reg], y1[reg], qa);
            qa = fmaf(y2[reg], y2[reg], qa);
            qa = fmaf(y3[reg], y3[reg], qa);
            qrow[reg] = qa;
        }
        #pragma unroll
        for (int off = 1; off < 16; off <<= 1) {
            #pragma unroll
            for (int reg = 0; reg < 4; ++reg) {
                srow[reg] += __shfl_xor(srow[reg], off, 64);
                qrow[reg] += __shfl_xor(qrow[reg], off, 64);
            }
        }
        float o[4];
        #pragma unroll
        for (int reg = 0; reg < 4; ++reg) {
            float mu2 = srow[reg] * (1.f / 64.f);
            float rs2 = rsqrtf(qrow[reg] * (1.f / 64.f) - mu2 * mu2 + LN_EPS);
            float nm2 = -mu2 * rs2;
            float t0 = fmaxf(fmaf(fmaf(y0[reg], rs2, nm2), g2c0, e2c0), 0.f);
            float t1 = fmaxf(fmaf(fmaf(y1[reg], rs2, nm2), g2c1, e2c1), 0.f);
            float t2 = fmaxf(fmaf(fmaf(y2[reg], rs2, nm2), g2c2, e2c2), 0.f);
            float t3 = fmaxf(fmaf(fmaf(y3[reg], rs2, nm2), g2c3, e2c3), 0.f);
            o[reg] = fmaf(t0, w3c0, fmaf(t1, w3c1, fmaf(t2, w3c2, t3 * w3c3)));
        }
        #pragma unroll
        for (int off = 1; off < 16; off <<= 1) {
            #pragma unroll
            for (int reg = 0; reg < 4; ++reg) o[reg] += __shfl_xor(o[reg], off, 64);
        }
        if (m == 0) {
            long rb = tcur * 16 + quad * 4;
            if (isf32) {
                float4 v = make_float4(o[0] + b3v, o[1] + b3v, o[2] + b3v, o[3] + b3v);
                *(float4*)((float*)out + rb) = v;
            } else {
                ushort4 v;
                v.x = f2bs(o[0] + b3v);
                v.y = f2bs(o[1] + b3v);
                v.z = f2bs(o[2] + b3v);
                v.w = f2bs(o[3] + b3v);
                *(ushort4*)((bf16*)out + rb) = v;
            }
        }
        if (!have_next) break;
    }
}

extern "C" __attribute__((visibility("default")))
void kernel_launch(void* const* d_in, const int* in_sizes, int n_in,
                   void* d_out, int out_size, void* d_ws, size_t ws_size,
                   hipStream_t stream) {
    const void* uE   = d_in[0];
    const void* iE   = d_in[1];
    const void* uHy  = d_in[2];
    const void* iHy  = d_in[3];
    const void* W1   = d_in[4];
    const void* b1   = d_in[5];
    const void* g1   = d_in[6];
    const void* be1  = d_in[7];
    const void* W2   = d_in[8];
    const void* b2   = d_in[9];
    const void* g2   = d_in[10];
    const void* be2  = d_in[11];
    const void* W3   = d_in[12];
    const void* b3   = d_in[13];
    const void* adj_vals = d_in[14];
    const int*  adj_rows = (const int*)d_in[15];
    const int*  adj_cols = (const int*)d_in[16];
    const int*  userIdx  = (const int*)d_in[17];
    const int*  servIdx  = (const int*)d_in[18];

    char* w = (char*)d_ws;
    size_t off = 0;
    auto alloc = [&](size_t bytes) -> char* {
        char* p = w + off;
        off += (bytes + 255) & ~(size_t)255;
        return p;
    };
    unsigned short* E0Hi = (unsigned short*)alloc((size_t)ET_U16 * 2);
    unsigned short* E0Lo = (unsigned short*)alloc((size_t)ET_U16 * 2);
    unsigned short* E1Hi = (unsigned short*)alloc((size_t)ET_U16 * 2);
    unsigned short* E1Lo = (unsigned short*)alloc((size_t)ET_U16 * 2);
    unsigned short* PkS  = (unsigned short*)alloc((size_t)PKS_U16 * 2);
    unsigned short* PkU  = (unsigned short*)alloc((size_t)PKU_U16 * 2);
    float* P    = (float*)alloc((size_t)2 * D_DIM * H_DIM * 4);
    float* A    = (float*)alloc((size_t)N_CNT * H_DIM * 4);
    int*   flag = (int*)alloc(256);
    float* Wf   = (float*)alloc((size_t)WF_TOT * 4);
    unsigned short* Wb = (unsigned short*)alloc((size_t)4096 * 2);

    k_detect<<<1, 64, 0, stream>>>(uE, flag);
    hipMemsetAsync(PkS, 0, (size_t)PKS_U16 * 2, stream);
    hipMemsetAsync(PkU, 0, (size_t)PKU_U16 * 2, stream);
    k_pre<<<(M_EDGE + 255) / 256, 256, 0, stream>>>(uE, iE, E0Hi, E0Lo,
                                                    adj_rows, adj_cols, adj_vals,
                                                    PkS, PkU, flag);
    // 3 hops: E0 -> E1 -> E0 -> E1 (MFMA GEMM)
    k_hop<<<HOP_BLOCKS, 512, 0, stream>>>(E0Hi, E0Lo, E1Hi, E1Lo, PkS, PkU);
    k_hop<<<HOP_BLOCKS, 512, 0, stream>>>(E1Hi, E1Lo, E0Hi, E0Lo, PkS, PkU);
    k_hop<<<HOP_BLOCKS, 512, 0, stream>>>(E0Hi, E0Lo, E1Hi, E1Lo, PkS, PkU);

    k_hyperP<<<9, 256, 0, stream>>>(uHy, iHy, W1, W2, b1, g1, be1, b2, g2, be2, W3, b3,
                                    P, Wf, Wb, flag);
    k_A<<<N_CNT, H_DIM, 0, stream>>>(E1Hi, E1Lo, P, Wf, A);

    HyperModel_65755949301857_kernel<<<MLP_BLOCKS, 256, 0, stream>>>(
        A, userIdx, servIdx, Wf, Wb, d_out, flag);
}